// Round 7
// baseline (152.200 us; speedup 1.0000x reference)
//
#include <hip/hip_runtime.h>
#include <hip/hip_bf16.h>
#include <math.h>

#define EMBD 768
#define FFN_HID 2048
#define HEAD_DIM 64
#define KV_H 5
#define KV_DIM 320
#define Q_H 15
#define QDIM (Q_H * HEAD_DIM) /* 960 */
#define BB 4
#define LL 512
#define LC 2048
#define EPSV 1.1920929e-07f
#define NSP 8

typedef __attribute__((ext_vector_type(8))) __bf16 bf16x8;
typedef __attribute__((ext_vector_type(2))) __bf16 bf16x2;
typedef __attribute__((ext_vector_type(8))) short short8;
typedef __attribute__((ext_vector_type(4))) float floatx4;
typedef __attribute__((ext_vector_type(2))) unsigned uint2v;
typedef __attribute__((ext_vector_type(4))) unsigned uint4v;
typedef unsigned short ushort;

// 0.125 (1/sqrt(64)) * log2(e), folded into q at projection time
#define RSCALE 0.18033688011112042f

__device__ inline ushort f2bf(float f) {
  union { float f; unsigned u; } c; c.f = f;
  return (ushort)((c.u + 0x8000u) >> 16);
}
__device__ inline float bf2f(ushort s) {
  union { unsigned u; float f; } c; c.u = ((unsigned)s) << 16;
  return c.f;
}
#if __has_builtin(__builtin_amdgcn_cvt_pk_bf16_f32)
__device__ inline unsigned pk2bf(float a, float b) {
  union { bf16x2 v; unsigned u; } c;
  c.v = __builtin_amdgcn_cvt_pk_bf16_f32(a, b);
  return c.u;
}
#else
__device__ inline unsigned pk2bf(float a, float b) {
  union { float f; unsigned u; } x, y; x.f = a; y.f = b;
  return ((x.u + 0x8000u) >> 16) | ((y.u + 0x8000u) & 0xffff0000u);
}
#endif

__device__ __forceinline__ void glds16(const ushort* g, ushort* l) {
  __builtin_amdgcn_global_load_lds(
      (const __attribute__((address_space(1))) unsigned int*)g,
      (__attribute__((address_space(3))) unsigned int*)l, 16, 0, 0);
}

// ---------------- mega prep: weight transposes + rmsnorm1 + SS zero, one dispatch ----------------
// mode 0: transpose fp32 W[K][N] -> bf16 Wt[N][K] (per 64x64 tile)
// mode 2: rmsnorm row (aux = ln weight), one row per block
// mode 3: zero fp32 buffer (1024 floats per block)
struct MD { const void* src; void* dst; const float* aux; int K; int N; int nx; int base; int mode; };
struct MD10 { MD d[10]; };

__global__ __launch_bounds__(256) void mega_prep(MD10 ds) {
  int bid = blockIdx.x;
  int sel = 0;
#pragma unroll
  for (int j = 1; j < 10; ++j) sel = (bid >= ds.d[j].base) ? j : sel;
  MD t = ds.d[sel];
  int rel = bid - t.base;
  int tid = threadIdx.x;
  if (t.mode == 3) {  // zero
    float4 z = {0.f, 0.f, 0.f, 0.f};
    *(float4*)((float*)t.dst + ((size_t)rel * 256 + tid) * 4) = z;
    return;
  }
  if (t.mode == 2) {  // rmsnorm row
    const float* xr = (const float*)t.src + (size_t)rel * EMBD;
    ushort* orow = (ushort*)t.dst + (size_t)rel * EMBD;
    float ss = 0.f;
    for (int i = tid; i < EMBD; i += 256) { float v = xr[i]; ss += v * v; }
    for (int off = 32; off > 0; off >>= 1) ss += __shfl_down(ss, off, 64);
    __shared__ float sred[4];
    if ((tid & 63) == 0) sred[tid >> 6] = ss;
    __syncthreads();
    float tot = sred[0] + sred[1] + sred[2] + sred[3];
    float scale = rsqrtf(tot * (1.0f / EMBD) + EPSV);
    for (int i = tid; i < EMBD; i += 256) orow[i] = f2bf(xr[i] * scale * t.aux[i]);
    return;
  }
  // mode 0: weight transpose tile
  int bx = rel % t.nx, by = rel / t.nx;
  int k0 = by * 64, n0 = bx * 64;
  __shared__ ushort T[64][72];
  int r = tid >> 2, cb = (tid & 3) * 16;
#pragma unroll
  for (int i = 0; i < 16; i += 4) {
    float4 f = *(const float4*)((const float*)t.src + (size_t)(k0 + r) * t.N + n0 + cb + i);
    T[r][cb + i + 0] = f2bf(f.x); T[r][cb + i + 1] = f2bf(f.y);
    T[r][cb + i + 2] = f2bf(f.z); T[r][cb + i + 3] = f2bf(f.w);
  }
  __syncthreads();
#pragma unroll
  for (int i = 0; i < 2; ++i) {
    short8 v;
#pragma unroll
    for (int j = 0; j < 8; ++j) v[j] = (short)T[cb + i * 8 + j][r];
    *(short8*)((ushort*)t.dst + (size_t)(n0 + r) * t.K + k0 + cb + i * 8) = v;
  }
}

// ---- 128x64-tile GEMM, K chunk-paired, f32 out + residual ----
__global__ __launch_bounds__(256) void gemm128r(const ushort* __restrict__ A,
                                                const ushort* __restrict__ Bt,
                                                const float* __restrict__ Rf,
                                                float* __restrict__ Cout,
                                                int M, int N, int K) {
  __shared__ ushort As[2][128 * 64];
  __shared__ ushort Bs[2][64 * 64];
  int tid = threadIdx.x;
  int w = tid >> 6, lane = tid & 63;
  int lm = lane & 15, lq = lane >> 4;
  int m0 = blockIdx.y * 128, n0 = blockIdx.x * 64;
  int wm = (w & 1) * 64, wn = (w >> 1) * 32;
  int arow = lane >> 3, acol = ((lane & 7) ^ arow) << 3;
  int kg[2] = {((lq) ^ (lm & 7)) << 3, ((4 + lq) ^ (lm & 7)) << 3};
  floatx4 acc[4][2];
#pragma unroll
  for (int i = 0; i < 4; ++i)
#pragma unroll
    for (int j = 0; j < 2; ++j) acc[i][j] = (floatx4){0.f, 0.f, 0.f, 0.f};
  for (int k0 = 0; k0 < K; k0 += 128) {
    int two = (k0 + 64 < K) ? 1 : 0;  // block-uniform
#pragma unroll 2
    for (int c = 0; c <= two; ++c) {
      int kk = k0 + c * 64;
#pragma unroll
      for (int s = 0; s < 4; ++s) {
        int g = (w << 2) + s;
        glds16(A + (size_t)(m0 + g * 8 + arow) * K + kk + acol, &As[c][g * 512]);
      }
#pragma unroll
      for (int s = 0; s < 2; ++s) {
        int g = (w << 1) + s;
        glds16(Bt + (size_t)(n0 + g * 8 + arow) * K + kk + acol, &Bs[c][g * 512]);
      }
    }
    __syncthreads();
#pragma unroll 2
    for (int c = 0; c <= two; ++c) {
#pragma unroll
      for (int kc = 0; kc < 2; ++kc) {
        bf16x8 af[4], bf[2];
#pragma unroll
        for (int mt = 0; mt < 4; ++mt)
          af[mt] = *(const bf16x8*)&As[c][(wm + mt * 16 + lm) * 64 + kg[kc]];
#pragma unroll
        for (int nt = 0; nt < 2; ++nt)
          bf[nt] = *(const bf16x8*)&Bs[c][(wn + nt * 16 + lm) * 64 + kg[kc]];
#pragma unroll
        for (int mt = 0; mt < 4; ++mt)
#pragma unroll
          for (int nt = 0; nt < 2; ++nt)
            acc[mt][nt] = __builtin_amdgcn_mfma_f32_16x16x32_bf16(af[mt], bf[nt], acc[mt][nt], 0, 0, 0);
      }
    }
    __syncthreads();
  }
#pragma unroll
  for (int mt = 0; mt < 4; ++mt)
#pragma unroll
    for (int nt = 0; nt < 2; ++nt)
#pragma unroll
      for (int r = 0; r < 4; ++r) {
        int row = m0 + wm + mt * 16 + lq * 4 + r;
        int col = n0 + wn + nt * 16 + lm;
        size_t idx = (size_t)row * N + col;
        Cout[idx] = acc[mt][nt][r] + Rf[idx];
      }
}

// ---- as gemm128r, plus per-row sum-of-squares accumulation into SS (for fused rmsnorm2) ----
__global__ __launch_bounds__(256) void gemm128r_ss(const ushort* __restrict__ A,
                                                   const ushort* __restrict__ Bt,
                                                   const float* __restrict__ Rf,
                                                   float* __restrict__ Cout,
                                                   float* __restrict__ SS,
                                                   int M, int N, int K) {
  __shared__ ushort As[2][128 * 64];
  __shared__ ushort Bs[2][64 * 64];
  int tid = threadIdx.x;
  int w = tid >> 6, lane = tid & 63;
  int lm = lane & 15, lq = lane >> 4;
  int m0 = blockIdx.y * 128, n0 = blockIdx.x * 64;
  int wm = (w & 1) * 64, wn = (w >> 1) * 32;
  int arow = lane >> 3, acol = ((lane & 7) ^ arow) << 3;
  int kg[2] = {((lq) ^ (lm & 7)) << 3, ((4 + lq) ^ (lm & 7)) << 3};
  floatx4 acc[4][2];
#pragma unroll
  for (int i = 0; i < 4; ++i)
#pragma unroll
    for (int j = 0; j < 2; ++j) acc[i][j] = (floatx4){0.f, 0.f, 0.f, 0.f};
  for (int k0 = 0; k0 < K; k0 += 128) {
    int two = (k0 + 64 < K) ? 1 : 0;
#pragma unroll 2
    for (int c = 0; c <= two; ++c) {
      int kk = k0 + c * 64;
#pragma unroll
      for (int s = 0; s < 4; ++s) {
        int g = (w << 2) + s;
        glds16(A + (size_t)(m0 + g * 8 + arow) * K + kk + acol, &As[c][g * 512]);
      }
#pragma unroll
      for (int s = 0; s < 2; ++s) {
        int g = (w << 1) + s;
        glds16(Bt + (size_t)(n0 + g * 8 + arow) * K + kk + acol, &Bs[c][g * 512]);
      }
    }
    __syncthreads();
#pragma unroll 2
    for (int c = 0; c <= two; ++c) {
#pragma unroll
      for (int kc = 0; kc < 2; ++kc) {
        bf16x8 af[4], bf[2];
#pragma unroll
        for (int mt = 0; mt < 4; ++mt)
          af[mt] = *(const bf16x8*)&As[c][(wm + mt * 16 + lm) * 64 + kg[kc]];
#pragma unroll
        for (int nt = 0; nt < 2; ++nt)
          bf[nt] = *(const bf16x8*)&Bs[c][(wn + nt * 16 + lm) * 64 + kg[kc]];
#pragma unroll
        for (int mt = 0; mt < 4; ++mt)
#pragma unroll
          for (int nt = 0; nt < 2; ++nt)
            acc[mt][nt] = __builtin_amdgcn_mfma_f32_16x16x32_bf16(af[mt], bf[nt], acc[mt][nt], 0, 0, 0);
      }
    }
    __syncthreads();
  }
#pragma unroll
  for (int mt = 0; mt < 4; ++mt)
#pragma unroll
    for (int r = 0; r < 4; ++r) {
      int row = m0 + wm + mt * 16 + lq * 4 + r;
      float s2 = 0.f;
#pragma unroll
      for (int nt = 0; nt < 2; ++nt) {
        int col = n0 + wn + nt * 16 + lm;
        size_t idx = (size_t)row * N + col;
        float vv = acc[mt][nt][r] + Rf[idx];
        Cout[idx] = vv;
        s2 += vv * vv;
      }
      s2 += __shfl_xor(s2, 1, 64);
      s2 += __shfl_xor(s2, 2, 64);
      s2 += __shfl_xor(s2, 4, 64);
      s2 += __shfl_xor(s2, 8, 64);
      if (lm == 0) atomicAdd(&SS[row], s2);  // device-scope, cross-XCD safe
    }
}

// ============ merged kv-proj (fp32 A, in-flight convert) + q-proj/RoPE ============
__global__ __launch_bounds__(256) void kvq_kernel(const float* __restrict__ tk,
                                                  const float* __restrict__ tv,
                                                  const ushort* __restrict__ Btk,
                                                  const ushort* __restrict__ Btv,
                                                  const ushort* __restrict__ xnorm,
                                                  const ushort* __restrict__ wqt,
                                                  ushort* __restrict__ Ck,
                                                  ushort* __restrict__ Vt,
                                                  ushort* __restrict__ Q) {
  __shared__ ushort As[128 * 64];
  __shared__ ushort Bs[64 * 64];
  int bid = blockIdx.x;
  int tid = threadIdx.x;
  int w = tid >> 6, lane = tid & 63;
  int lm = lane & 15, lq = lane >> 4;
  int arow = lane >> 3, acol = ((lane & 7) ^ arow) << 3;
  int kg[2] = {((lq) ^ (lm & 7)) << 3, ((4 + lq) ^ (lm & 7)) << 3};

  if (bid < 640) {
    int bz = bid / 320;
    int rem = bid - bz * 320;
    int bx = rem % 5, by = rem / 5;
    const float* Af = bz ? tv : tk;
    const ushort* Bt = bz ? Btv : Btk;
    int m0 = by * 128, n0 = bx * 64;
    int wm = (w & 1) * 64, wn = (w >> 1) * 32;
    floatx4 acc[4][2];
#pragma unroll
    for (int i = 0; i < 4; ++i)
#pragma unroll
      for (int j = 0; j < 2; ++j) acc[i][j] = (floatx4){0.f, 0.f, 0.f, 0.f};
    for (int k0 = 0; k0 < KV_DIM; k0 += 64) {
#pragma unroll
      for (int s = 0; s < 4; ++s) {
        int rr = ((w << 2) + s) * 8 + arow;
        const float* src = Af + (size_t)(m0 + rr) * KV_DIM + k0 + ((lane & 7) << 3);
        float4 a0 = *(const float4*)src;
        float4 a1 = *(const float4*)(src + 4);
        uint4v pv = (uint4v){pk2bf(a0.x, a0.y), pk2bf(a0.z, a0.w),
                             pk2bf(a1.x, a1.y), pk2bf(a1.z, a1.w)};
        *(uint4v*)&As[rr * 64 + (((lane & 7) ^ arow) << 3)] = pv;
      }
#pragma unroll
      for (int s = 0; s < 2; ++s) {
        int g = (w << 1) + s;
        glds16(Bt + (size_t)(n0 + g * 8 + arow) * KV_DIM + k0 + acol, &Bs[g * 512]);
      }
      __syncthreads();
#pragma unroll
      for (int kc = 0; kc < 2; ++kc) {
        bf16x8 af[4], bf[2];
#pragma unroll
        for (int mt = 0; mt < 4; ++mt)
          af[mt] = *(const bf16x8*)&As[(wm + mt * 16 + lm) * 64 + kg[kc]];
#pragma unroll
        for (int nt = 0; nt < 2; ++nt)
          bf[nt] = *(const bf16x8*)&Bs[(wn + nt * 16 + lm) * 64 + kg[kc]];
#pragma unroll
        for (int mt = 0; mt < 4; ++mt)
#pragma unroll
          for (int nt = 0; nt < 2; ++nt)
            acc[mt][nt] = __builtin_amdgcn_mfma_f32_16x16x32_bf16(af[mt], bf[nt], acc[mt][nt], 0, 0, 0);
      }
      __syncthreads();
    }
    if (bz == 0) {  // K: row-major [token][KV_DIM]
#pragma unroll
      for (int mt = 0; mt < 4; ++mt)
#pragma unroll
        for (int nt = 0; nt < 2; ++nt)
#pragma unroll
          for (int r = 0; r < 4; ++r) {
            int row = m0 + wm + mt * 16 + lq * 4 + r;
            int col = n0 + wn + nt * 16 + lm;
            Ck[(size_t)row * KV_DIM + col] = f2bf(acc[mt][nt][r]);
          }
    } else {  // V: write transposed vt[(b*5+kvh)*64+d][token], 4 tokens packed
      int kvh = bx;
#pragma unroll
      for (int mt = 0; mt < 4; ++mt)
#pragma unroll
        for (int nt = 0; nt < 2; ++nt) {
          int d = wn + nt * 16 + lm;
          int grow = m0 + wm + mt * 16 + lq * 4;  // token base, 4-aligned
          int b = grow >> 11;
          int tok = grow & (LC - 1);
          size_t a = ((size_t)(b * KV_H + kvh) * 64 + d) * LC + tok;
          uint2v pk = (uint2v){pk2bf(acc[mt][nt][0], acc[mt][nt][1]),
                               pk2bf(acc[mt][nt][2], acc[mt][nt][3])};
          *(uint2v*)&Vt[a] = pk;
        }
    }
    return;
  }

  // ---- q projection + fused RoPE ----
  int r0 = bid - 640;
  int bx = r0 % 15, by = r0 / 15;
  int m0 = by * 128, n0 = bx * 64;
  int wm = (w & 1) * 64, wn = (w >> 1) * 16;  // cols wn+lm and +32
  floatx4 acc[4][2];
#pragma unroll
  for (int i = 0; i < 4; ++i)
#pragma unroll
    for (int j = 0; j < 2; ++j) acc[i][j] = (floatx4){0.f, 0.f, 0.f, 0.f};
  for (int k0 = 0; k0 < EMBD; k0 += 64) {
#pragma unroll
    for (int s = 0; s < 4; ++s) {
      int g = (w << 2) + s;
      glds16(xnorm + (size_t)(m0 + g * 8 + arow) * EMBD + k0 + acol, &As[g * 512]);
    }
#pragma unroll
    for (int s = 0; s < 2; ++s) {
      int g = (w << 1) + s;
      glds16(wqt + (size_t)(n0 + g * 8 + arow) * EMBD + k0 + acol, &Bs[g * 512]);
    }
    __syncthreads();
#pragma unroll
    for (int kc = 0; kc < 2; ++kc) {
      bf16x8 af[4], bf[2];
#pragma unroll
      for (int mt = 0; mt < 4; ++mt)
        af[mt] = *(const bf16x8*)&As[(wm + mt * 16 + lm) * 64 + kg[kc]];
#pragma unroll
      for (int nt = 0; nt < 2; ++nt) {
        int br = wn + nt * 32 + lm;
        bf[nt] = *(const bf16x8*)&Bs[br * 64 + (((kc * 4 + lq) ^ (br & 7)) << 3)];
      }
#pragma unroll
      for (int mt = 0; mt < 4; ++mt)
#pragma unroll
        for (int nt = 0; nt < 2; ++nt)
          acc[mt][nt] = __builtin_amdgcn_mfma_f32_16x16x32_bf16(af[mt], bf[nt], acc[mt][nt], 0, 0, 0);
    }
    __syncthreads();
  }
  int d = wn + lm;  // 0..31
  float invts = exp2f(-(float)d * 0.4152410118609203f);  // 10000^(-d/32)
#pragma unroll
  for (int mt = 0; mt < 4; ++mt)
#pragma unroll
    for (int r = 0; r < 4; ++r) {
      int row = m0 + wm + mt * 16 + lq * 4 + r;
      int l = row & (LL - 1);
      float th = (float)l * invts;
      float s, c;
      __sincosf(th, &s, &c);
      float q1 = acc[mt][0][r], q2 = acc[mt][1][r];
      size_t base = (size_t)row * QDIM + n0 + d;
      Q[base] = f2bf((q1 * c - q2 * s) * RSCALE);
      Q[base + 32] = f2bf((q2 * c + q1 * s) * RSCALE);
    }
}

// ---- fused rmsnorm2 + gate+up: r5 single-buffer structure (32 KB LDS, 5 blocks/CU),
// A staged from fp32 x2 with inline scale = rsqrt(SS[row]/768+eps) * ln2_w[k]
// (reg-staged cvt_pk + swizzled ds_write; store invariant LDS col c = global col c^(row&7)). ----
__global__ __launch_bounds__(256) void gemm_gateup(const float* __restrict__ x2,
                                                   const float* __restrict__ SS,
                                                   const float* __restrict__ ln2w,
                                                   const ushort* __restrict__ Bg,
                                                   const ushort* __restrict__ Bu,
                                                   ushort* __restrict__ H,
                                                   int M, int N, int K) {
  __shared__ ushort As[128 * 64];
  __shared__ ushort Bs0[64 * 64];
  __shared__ ushort Bs1[64 * 64];
  int tid = threadIdx.x;
  int w = tid >> 6, lane = tid & 63;
  int lm = lane & 15, lq = lane >> 4;
  int m0 = blockIdx.y * 128, n0 = blockIdx.x * 64;
  int wm = (w & 1) * 64, wn = (w >> 1) * 32;
  int arow = lane >> 3, acol = ((lane & 7) ^ arow) << 3;
  int kg[2] = {((lq) ^ (lm & 7)) << 3, ((4 + lq) ^ (lm & 7)) << 3};
  // hoisted per-row rmsnorm scales for this thread's 4 staged rows (constant over K)
  float scl[4];
#pragma unroll
  for (int s = 0; s < 4; ++s) {
    int rr = ((w << 2) + s) * 8 + arow;
    scl[s] = rsqrtf(SS[m0 + rr] * (1.0f / EMBD) + EPSV);
  }
  floatx4 accg[4][2], accu[4][2];
#pragma unroll
  for (int i = 0; i < 4; ++i)
#pragma unroll
    for (int j = 0; j < 2; ++j) {
      accg[i][j] = (floatx4){0.f, 0.f, 0.f, 0.f};
      accu[i][j] = (floatx4){0.f, 0.f, 0.f, 0.f};
    }
  for (int k0 = 0; k0 < K; k0 += 64) {
    int kkg = k0 + ((lane & 7) << 3);
    float4 lw0 = *(const float4*)(ln2w + kkg);
    float4 lw1 = *(const float4*)(ln2w + kkg + 4);
#pragma unroll
    for (int s = 0; s < 4; ++s) {
      int rr = ((w << 2) + s) * 8 + arow;
      const float* src = x2 + (size_t)(m0 + rr) * K + kkg;
      float4 a0 = *(const float4*)src;
      float4 a1 = *(const float4*)(src + 4);
      float sc = scl[s];
      uint4v pv = (uint4v){pk2bf(a0.x * lw0.x * sc, a0.y * lw0.y * sc),
                           pk2bf(a0.z * lw0.z * sc, a0.w * lw0.w * sc),
                           pk2bf(a1.x * lw1.x * sc, a1.y * lw1.y * sc),
                           pk2bf(a1.z * lw1.z * sc, a1.w * lw1.w * sc)};
      *(uint4v*)&As[rr * 64 + (((lane & 7) ^ arow) << 3)] = pv;
    }
#pragma unroll
    for (int s = 0; s < 2; ++s) {
      int g = (w << 1) + s;
      glds16(Bg + (size_t)(n0 + g * 8 + arow) * K + k0 + acol, &Bs0[g * 512]);
      glds16(Bu + (size_t)(n0 + g * 8 + arow) * K + k0 + acol, &Bs1[g * 512]);
    }
    __syncthreads();
#pragma unroll
    for (int kc = 0; kc < 2; ++kc) {
      bf16x8 af[4], bg[2], bu[2];
#pragma unroll
      for (int mt = 0; mt < 4; ++mt)
        af[mt] = *(const bf16x8*)&As[(wm + mt * 16 + lm) * 64 + kg[kc]];
#pragma unroll
      for (int nt = 0; nt < 2; ++nt) {
        bg[nt] = *(const bf16x8*)&Bs0[(wn + nt * 16 + lm) * 64 + kg[kc]];
        bu[nt] = *(const bf16x8*)&Bs1[(wn + nt * 16 + lm) * 64 + kg[kc]];
      }
#pragma unroll
      for (int mt = 0; mt < 4; ++mt)
#pragma unroll
        for (int nt = 0; nt < 2; ++nt) {
          accg[mt][nt] = __builtin_amdgcn_mfma_f32_16x16x32_bf16(af[mt], bg[nt], accg[mt][nt], 0, 0, 0);
          accu[mt][nt] = __builtin_amdgcn_mfma_f32_16x16x32_bf16(af[mt], bu[nt], accu[mt][nt], 0, 0, 0);
        }
    }
    __syncthreads();
  }
#pragma unroll
  for (int mt = 0; mt < 4; ++mt)
#pragma unroll
    for (int nt = 0; nt < 2; ++nt)
#pragma unroll
      for (int r = 0; r < 4; ++r) {
        int row = m0 + wm + mt * 16 + lq * 4 + r;
        int col = n0 + wn + nt * 16 + lm;
        float gv = accg[mt][nt][r];
        float hv = gv / (1.f + __expf(-gv)) * accu[mt][nt][r];
        H[(size_t)row * N + col] = f2bf(hv);
      }
}

// ============ MFMA flash attention: 128-q blocks, NSP=8 ============
__global__ __launch_bounds__(256) void attn_kernel(const ushort* __restrict__ qb,
                                                   const ushort* __restrict__ kb,
                                                   const ushort* __restrict__ vt,
                                                   ushort* __restrict__ Op,
                                                   float* __restrict__ Ml) {
  int bid = blockIdx.x;
  int sp = bid & 7;
  int qt = (bid >> 3) & 3;
  int g = bid >> 5;  // 0..59
  int b = g / 15, h = g - b * 15;
  int kvh = h / 3;
  int l0 = qt * 128;
  int kv0 = sp * 256;
  __shared__ ushort Ks[64 * 64];
  __shared__ ushort Vs[64 * 64];
  __shared__ ushort Ps[4][32][72];           // 18432 B; per-wave P[32 q][64 keys]
  ushort* Qs = &Ps[0][0][0];                 // alias: 16 KB Q staging (dead after preload)
  int tid = threadIdx.x;
  int w = tid >> 6, lane = tid & 63, lm = lane & 15, lq = lane >> 4;
  int arow = lane >> 3, acol = ((lane & 7) ^ arow) << 3;
  int kg[2] = {((lq) ^ (lm & 7)) << 3, ((4 + lq) ^ (lm & 7)) << 3};
  const ushort* kbase = kb + (size_t)b * LC * KV_DIM + kvh * HEAD_DIM;
  const ushort* vbase = vt + (size_t)(b * KV_H + kvh) * 64 * LC;
#pragma unroll
  for (int s = 0; s < 4; ++s) {
    int gg = (w << 2) + s;
    glds16(qb + (size_t)(b * LL + l0 + gg * 8 + arow) * QDIM + h * HEAD_DIM + acol, &Qs[gg * 512]);
  }
  __syncthreads();
  bf16x8 aq[2][2];
#pragma unroll
  for (int q2 = 0; q2 < 2; ++q2) {
    int qr = w * 32 + q2 * 16 + lm;
    aq[q2][0] = *(const bf16x8*)&Qs[qr * 64 + kg[0]];
    aq[q2][1] = *(const bf16x8*)&Qs[qr * 64 + kg[1]];
  }
  bf16x8 bones;
  {
    short8 o = {0x3F80, 0x3F80, 0x3F80, 0x3F80, 0x3F80, 0x3F80, 0x3F80, 0x3F80};
    bones = *(bf16x8*)&o;
  }
  floatx4 oacc[4][2];  // [d-tile][q2]
#pragma unroll
  for (int i = 0; i < 4; ++i)
#pragma unroll
    for (int j = 0; j < 2; ++j) oacc[i][j] = (floatx4){0.f, 0.f, 0.f, 0.f};
  floatx4 lacc[2] = {(floatx4){0.f, 0.f, 0.f, 0.f}, (floatx4){0.f, 0.f, 0.f, 0.f}};

  for (int t = 0; t < 4; ++t) {
    int m0 = kv0 + t * 64;
#pragma unroll
    for (int s = 0; s < 2; ++s) {
      int gg = (w << 1) + s;
      glds16(kbase + (size_t)(m0 + gg * 8 + arow) * KV_DIM + acol, &Ks[gg * 512]);
      glds16(vbase + (size_t)(gg * 8 + arow) * LC + m0 + acol, &Vs[gg * 512]);
    }
    __syncthreads();  // also fences Qs->Ps alias on first iteration (aq reads drained)

    floatx4 sacc[4][2];
#pragma unroll
    for (int nt = 0; nt < 4; ++nt)
#pragma unroll
      for (int q2 = 0; q2 < 2; ++q2) sacc[nt][q2] = (floatx4){0.f, 0.f, 0.f, 0.f};
#pragma unroll
    for (int kc = 0; kc < 2; ++kc) {
#pragma unroll
      for (int nt = 0; nt < 4; ++nt) {
        bf16x8 bk = *(const bf16x8*)&Ks[(nt * 16 + lm) * 64 + kg[kc]];  // reused x2
#pragma unroll
        for (int q2 = 0; q2 < 2; ++q2)
          sacc[nt][q2] = __builtin_amdgcn_mfma_f32_16x16x32_bf16(bk, aq[q2][kc], sacc[nt][q2], 0, 0, 0);
      }
    }
#pragma unroll
    for (int nt = 0; nt < 4; ++nt)
#pragma unroll
      for (int q2 = 0; q2 < 2; ++q2) {
        float p0 = exp2f(sacc[nt][q2][0]);
        float p1 = exp2f(sacc[nt][q2][1]);
        float p2 = exp2f(sacc[nt][q2][2]);
        float p3 = exp2f(sacc[nt][q2][3]);
        uint2v pk = (uint2v){pk2bf(p0, p1), pk2bf(p2, p3)};
        *(uint2v*)&Ps[w][q2 * 16 + lm][nt * 16 + lq * 4] = pk;
      }
#pragma unroll
    for (int kc2 = 0; kc2 < 2; ++kc2) {
      bf16x8 ap[2];
      ap[0] = *(const bf16x8*)&Ps[w][lm][kc2 * 32 + lq * 8];
      ap[1] = *(const bf16x8*)&Ps[w][16 + lm][kc2 * 32 + lq * 8];
#pragma unroll
      for (int dt = 0; dt < 4; ++dt) {
        bf16x8 bv = *(const bf16x8*)&Vs[(dt * 16 + lm) * 64 + kg[kc2]];
#pragma unroll
        for (int q2 = 0; q2 < 2; ++q2)
          oacc[dt][q2] = __builtin_amdgcn_mfma_f32_16x16x32_bf16(ap[q2], bv, oacc[dt][q2], 0, 0, 0);
      }
      lacc[0] = __builtin_amdgcn_mfma_f32_16x16x32_bf16(ap[0], bones, lacc[0], 0, 0, 0);
      lacc[1] = __builtin_amdgcn_mfma_f32_16x16x32_bf16(ap[1], bones, lacc[1], 0, 0, 0);
    }
    __syncthreads();
  }
#pragma unroll
  for (int q2 = 0; q2 < 2; ++q2)
#pragma unroll
    for (int r = 0; r < 4; ++r) {
      int row = l0 + w * 32 + q2 * 16 + lq * 4 + r;
      size_t base = ((size_t)sp * (BB * LL) + b * LL + row) * QDIM + h * HEAD_DIM;
#pragma unroll
      for (int dt = 0; dt < 4; ++dt) Op[base + dt * 16 + lm] = f2bf(oacc[dt][q2][r]);
      if (lm == 0) Ml[((size_t)sp * (BB * LL) + b * LL + row) * Q_H + h] = lacc[q2][r];
    }
}

// combine NSP split partials -> ctx (vectorized short8; 2 rows per block)
__global__ __launch_bounds__(256) void combine_kernel(ushort* __restrict__ Op,
                                                      const float* __restrict__ Ml,
                                                      ushort* __restrict__ ctx) {
  int t = threadIdx.x;
  int half = t >> 7;
  int t2 = t & 127;
  if (t2 >= 120) return;
  int bl = blockIdx.x * 2 + half;
  int h = t2 >> 3;
  float lsum = 0.f;
#pragma unroll
  for (int s = 0; s < NSP; ++s) lsum += Ml[((size_t)s * (BB * LL) + bl) * Q_H + h];
  float inv = 1.f / lsum;
  size_t i0 = (size_t)bl * QDIM + t2 * 8;
  float o[8] = {0.f, 0.f, 0.f, 0.f, 0.f, 0.f, 0.f, 0.f};
#pragma unroll
  for (int s = 0; s < NSP; ++s) {
    short8 v = *(const short8*)(Op + (size_t)s * (BB * LL) * QDIM + i0);
#pragma unroll
    for (int j = 0; j < 8; ++j) o[j] += bf2f((ushort)v[j]);
  }
  short8 r;
#pragma unroll
  for (int j = 0; j < 8; ++j) r[j] = (short)f2bf(o[j] * inv);
  *(short8*)(ctx + i0) = r;
}

extern "C" void kernel_launch(void* const* d_in, const int* in_sizes, int n_in,
                              void* d_out, int out_size, void* d_ws, size_t ws_size,
                              hipStream_t stream) {
  const float* x      = (const float*)d_in[0];
  const float* text_k = (const float*)d_in[1];
  const float* text_v = (const float*)d_in[2];
  const float* ln1_w  = (const float*)d_in[3];
  const float* ln2_w  = (const float*)d_in[4];
  const float* wq     = (const float*)d_in[5];
  const float* wk     = (const float*)d_in[6];
  const float* wv     = (const float*)d_in[7];
  const float* wo     = (const float*)d_in[8];
  const float* w_gate = (const float*)d_in[9];
  const float* w_up   = (const float*)d_in[10];
  const float* w_down = (const float*)d_in[11];
  float* out = (float*)d_out;
  char* base = (char*)d_ws;

  const int BL = BB * LL;   // 2048

  ushort* xnorm = (ushort*)(base + 0);          // 3,145,728
  ushort* wqt   = (ushort*)(base + 3145728);    // 1,474,560
  ushort* wkt   = (ushort*)(base + 4620288);    //   204,800
  ushort* wvt   = (ushort*)(base + 4825088);    //   204,800
  ushort* wot   = (ushort*)(base + 5029888);    // 1,474,560
  ushort* wgt   = (ushort*)(base + 6504448);    // 3,145,728
  ushort* wut   = (ushort*)(base + 9650176);    // 3,145,728
  ushort* wdt   = (ushort*)(base + 12795904);   // 3,145,728
  ushort* kbuf  = (ushort*)(base + 15941632);   // 5,242,880
  ushort* vtb   = (ushort*)(base + 21184512);   // 5,242,880
  float*  x2    = (float*) (base + 26427392);   // 6,291,456
  ushort* qb    = (ushort*)(base + 32718848);   // 3,932,160
  float*  Ml    = (float*) (base + 47136768);   //   983,040 (NSP=8 x 122,880)
  float*  SS    = (float*) (base + 48119808);   //     8,192 (per-row sumsq for rmsnorm2)
  char* SCR = base + 48128000;
  ushort* Op    = (ushort*)SCR;                 // NSP x 3,932,160 = 31,457,280
  ushort* ctxb  = (ushort*)SCR;                 // combine out, in-place over Op0
  ushort* gbuf  = (ushort*)(base + 15941632);   // alias kbuf+vtb (dead after attn)

  // mega prep: 7 weight transposes + rmsnorm1 + SS zero, one dispatch
  MD10 ds;
  ds.d[0] = {wq,     wqt,   nullptr, EMBD,    QDIM,    QDIM / 64,    0,    0};
  ds.d[1] = {wk,     wkt,   nullptr, KV_DIM,  KV_DIM,  KV_DIM / 64,  180,  0};
  ds.d[2] = {wv,     wvt,   nullptr, KV_DIM,  KV_DIM,  KV_DIM / 64,  205,  0};
  ds.d[3] = {wo,     wot,   nullptr, QDIM,    EMBD,    EMBD / 64,    230,  0};
  ds.d[4] = {w_gate, wgt,   nullptr, EMBD,    FFN_HID, FFN_HID / 64, 410,  0};
  ds.d[5] = {w_up,   wut,   nullptr, EMBD,    FFN_HID, FFN_HID / 64, 794,  0};
  ds.d[6] = {w_down, wdt,   nullptr, FFN_HID, EMBD,    EMBD / 64,    1178, 0};
  ds.d[7] = {x,      xnorm, ln1_w,   0, 0, 0, 1562, 2};
  ds.d[8] = {nullptr, SS,   nullptr, 0, 0, 0, 1562 + BL, 3};
  ds.d[9] = {nullptr, SS,   nullptr, 0, 0, 0, 0x7fffffff, 3};  // dead
  const int nmega = 1562 + BL + 2;  // 3612
  mega_prep<<<nmega, 256, 0, stream>>>(ds);

  // merged k/v projections (fp32 A, in-flight convert) + q projection/RoPE
  kvq_kernel<<<880, 256, 0, stream>>>(text_k, text_v, wkt, wvt, xnorm, wqt, kbuf, vtb, qb);

  // attention: 1920 blocks = 60 (b,h) x 4 q-tiles x 8 kv-splits; then combine
  attn_kernel<<<1920, 256, 0, stream>>>(qb, kbuf, vtb, Op, Ml);
  combine_kernel<<<BL / 2, 256, 0, stream>>>(Op, Ml, ctxb);

  // x2 = ctx @ wo + x  (fused residual + per-row sumsq for rmsnorm2)
  gemm128r_ss<<<dim3(EMBD / 64, BL / 128), 256, 0, stream>>>(ctxb, wot, x, x2, SS, BL, EMBD, QDIM);

  // h = silu(rmsnorm(x2) @ w_gate) * (rmsnorm(x2) @ w_up)  (rmsnorm fused into A-staging, 32KB LDS)
  gemm_gateup<<<dim3(FFN_HID / 64, BL / 128), 256, 0, stream>>>(x2, SS, ln2_w, wgt, wut, gbuf, BL, FFN_HID, EMBD);

  // out = h @ w_down + x2  (128-tile chunk-paired GEMM, fused residual)
  gemm128r<<<dim3(EMBD / 64, BL / 128), 256, 0, stream>>>(gbuf, wdt, x2, out, BL, EMBD, FFN_HID);
}

// Round 8
// 143.310 us; speedup vs baseline: 1.0620x; 1.0620x over previous
//
#include <hip/hip_runtime.h>
#include <hip/hip_bf16.h>
#include <math.h>

#define EMBD 768
#define FFN_HID 2048
#define HEAD_DIM 64
#define KV_H 5
#define KV_DIM 320
#define Q_H 15
#define QDIM (Q_H * HEAD_DIM) /* 960 */
#define BB 4
#define LL 512
#define LC 2048
#define EPSV 1.1920929e-07f
#define NSP 8

typedef __attribute__((ext_vector_type(8))) __bf16 bf16x8;
typedef __attribute__((ext_vector_type(2))) __bf16 bf16x2;
typedef __attribute__((ext_vector_type(8))) short short8;
typedef __attribute__((ext_vector_type(4))) float floatx4;
typedef __attribute__((ext_vector_type(2))) unsigned uint2v;
typedef __attribute__((ext_vector_type(4))) unsigned uint4v;
typedef unsigned short ushort;

// 0.125 (1/sqrt(64)) * log2(e), folded into q at projection time
#define RSCALE 0.18033688011112042f

__device__ inline ushort f2bf(float f) {
  union { float f; unsigned u; } c; c.f = f;
  return (ushort)((c.u + 0x8000u) >> 16);
}
__device__ inline float bf2f(ushort s) {
  union { unsigned u; float f; } c; c.u = ((unsigned)s) << 16;
  return c.f;
}
#if __has_builtin(__builtin_amdgcn_cvt_pk_bf16_f32)
__device__ inline unsigned pk2bf(float a, float b) {
  union { bf16x2 v; unsigned u; } c;
  c.v = __builtin_amdgcn_cvt_pk_bf16_f32(a, b);
  return c.u;
}
#else
__device__ inline unsigned pk2bf(float a, float b) {
  union { float f; unsigned u; } x, y; x.f = a; y.f = b;
  return ((x.u + 0x8000u) >> 16) | ((y.u + 0x8000u) & 0xffff0000u);
}
#endif

__device__ __forceinline__ void glds16(const ushort* g, ushort* l) {
  __builtin_amdgcn_global_load_lds(
      (const __attribute__((address_space(1))) unsigned int*)g,
      (__attribute__((address_space(3))) unsigned int*)l, 16, 0, 0);
}

// ---------------- RMSNorm fp32 in -> bf16 out (standalone, for x2) ----------------
__global__ __launch_bounds__(256) void rmsnorm_kernel(const float* __restrict__ x,
                                                      const float* __restrict__ w,
                                                      ushort* __restrict__ out) {
  int row = blockIdx.x;
  const float* xr = x + (size_t)row * EMBD;
  ushort* orow = out + (size_t)row * EMBD;
  int tid = threadIdx.x;
  float ss = 0.f;
  for (int i = tid; i < EMBD; i += 256) { float v = xr[i]; ss += v * v; }
  for (int off = 32; off > 0; off >>= 1) ss += __shfl_down(ss, off, 64);
  __shared__ float sred[4];
  if ((tid & 63) == 0) sred[tid >> 6] = ss;
  __syncthreads();
  float tot = sred[0] + sred[1] + sred[2] + sred[3];
  float scale = rsqrtf(tot * (1.0f / EMBD) + EPSV);
  for (int i = tid; i < EMBD; i += 256) orow[i] = f2bf(xr[i] * scale * w[i]);
}

// ---------------- mega prep: weight transposes + rmsnorm1, one dispatch ----------------
// mode 0: transpose fp32 W[K][N] -> bf16 Wt[N][K] (per 64x64 tile)
// mode 2: rmsnorm row (aux = ln weight), one row per block
// (text_k/v conversion folded into kvq_kernel's A-staging)
struct MD { const void* src; void* dst; const float* aux; int K; int N; int nx; int base; int mode; };
struct MD10 { MD d[10]; };

__global__ __launch_bounds__(256) void mega_prep(MD10 ds) {
  int bid = blockIdx.x;
  int sel = 0;
#pragma unroll
  for (int j = 1; j < 10; ++j) sel = (bid >= ds.d[j].base) ? j : sel;
  MD t = ds.d[sel];
  int rel = bid - t.base;
  int tid = threadIdx.x;
  if (t.mode == 2) {  // rmsnorm row
    const float* xr = (const float*)t.src + (size_t)rel * EMBD;
    ushort* orow = (ushort*)t.dst + (size_t)rel * EMBD;
    float ss = 0.f;
    for (int i = tid; i < EMBD; i += 256) { float v = xr[i]; ss += v * v; }
    for (int off = 32; off > 0; off >>= 1) ss += __shfl_down(ss, off, 64);
    __shared__ float sred[4];
    if ((tid & 63) == 0) sred[tid >> 6] = ss;
    __syncthreads();
    float tot = sred[0] + sred[1] + sred[2] + sred[3];
    float scale = rsqrtf(tot * (1.0f / EMBD) + EPSV);
    for (int i = tid; i < EMBD; i += 256) orow[i] = f2bf(xr[i] * scale * t.aux[i]);
    return;
  }
  // mode 0: weight transpose tile
  int bx = rel % t.nx, by = rel / t.nx;
  int k0 = by * 64, n0 = bx * 64;
  __shared__ ushort T[64][72];
  int r = tid >> 2, cb = (tid & 3) * 16;
#pragma unroll
  for (int i = 0; i < 16; i += 4) {
    float4 f = *(const float4*)((const float*)t.src + (size_t)(k0 + r) * t.N + n0 + cb + i);
    T[r][cb + i + 0] = f2bf(f.x); T[r][cb + i + 1] = f2bf(f.y);
    T[r][cb + i + 2] = f2bf(f.z); T[r][cb + i + 3] = f2bf(f.w);
  }
  __syncthreads();
#pragma unroll
  for (int i = 0; i < 2; ++i) {
    short8 v;
#pragma unroll
    for (int j = 0; j < 8; ++j) v[j] = (short)T[cb + i * 8 + j][r];
    *(short8*)((ushort*)t.dst + (size_t)(n0 + r) * t.K + k0 + cb + i * 8) = v;
  }
}

// ---- 128x64-tile GEMM, K chunk-paired (2x64 per barrier-pair), f32 out + residual ----
// 32 MFMA/wave per barrier-pair; handles K % 128 == 64 tails.
__global__ __launch_bounds__(256) void gemm128r(const ushort* __restrict__ A,
                                                const ushort* __restrict__ Bt,
                                                const float* __restrict__ Rf,
                                                float* __restrict__ Cout,
                                                int M, int N, int K) {
  __shared__ ushort As[2][128 * 64];
  __shared__ ushort Bs[2][64 * 64];
  int tid = threadIdx.x;
  int w = tid >> 6, lane = tid & 63;
  int lm = lane & 15, lq = lane >> 4;
  int m0 = blockIdx.y * 128, n0 = blockIdx.x * 64;
  int wm = (w & 1) * 64, wn = (w >> 1) * 32;
  int arow = lane >> 3, acol = ((lane & 7) ^ arow) << 3;
  int kg[2] = {((lq) ^ (lm & 7)) << 3, ((4 + lq) ^ (lm & 7)) << 3};
  floatx4 acc[4][2];
#pragma unroll
  for (int i = 0; i < 4; ++i)
#pragma unroll
    for (int j = 0; j < 2; ++j) acc[i][j] = (floatx4){0.f, 0.f, 0.f, 0.f};
  for (int k0 = 0; k0 < K; k0 += 128) {
    int two = (k0 + 64 < K) ? 1 : 0;  // block-uniform
#pragma unroll 2
    for (int c = 0; c <= two; ++c) {
      int kk = k0 + c * 64;
#pragma unroll
      for (int s = 0; s < 4; ++s) {
        int g = (w << 2) + s;
        glds16(A + (size_t)(m0 + g * 8 + arow) * K + kk + acol, &As[c][g * 512]);
      }
#pragma unroll
      for (int s = 0; s < 2; ++s) {
        int g = (w << 1) + s;
        glds16(Bt + (size_t)(n0 + g * 8 + arow) * K + kk + acol, &Bs[c][g * 512]);
      }
    }
    __syncthreads();
#pragma unroll 2
    for (int c = 0; c <= two; ++c) {
#pragma unroll
      for (int kc = 0; kc < 2; ++kc) {
        bf16x8 af[4], bf[2];
#pragma unroll
        for (int mt = 0; mt < 4; ++mt)
          af[mt] = *(const bf16x8*)&As[c][(wm + mt * 16 + lm) * 64 + kg[kc]];
#pragma unroll
        for (int nt = 0; nt < 2; ++nt)
          bf[nt] = *(const bf16x8*)&Bs[c][(wn + nt * 16 + lm) * 64 + kg[kc]];
#pragma unroll
        for (int mt = 0; mt < 4; ++mt)
#pragma unroll
          for (int nt = 0; nt < 2; ++nt)
            acc[mt][nt] = __builtin_amdgcn_mfma_f32_16x16x32_bf16(af[mt], bf[nt], acc[mt][nt], 0, 0, 0);
      }
    }
    __syncthreads();
  }
#pragma unroll
  for (int mt = 0; mt < 4; ++mt)
#pragma unroll
    for (int nt = 0; nt < 2; ++nt)
#pragma unroll
      for (int r = 0; r < 4; ++r) {
        int row = m0 + wm + mt * 16 + lq * 4 + r;
        int col = n0 + wn + nt * 16 + lm;
        size_t idx = (size_t)row * N + col;
        Cout[idx] = acc[mt][nt][r] + Rf[idx];
      }
}

// ============ merged kv-proj (fp32 A, in-flight convert) + q-proj/RoPE ============
// bid < 640: k/v projection 128x64 tiles (z-merged k/v); A = text_k/v fp32,
//   converted to bf16 during reg-staging (cvt_pk + swizzled ds_write_b128).
//   LDS content mapping identical to the glds pre-swizzled-source path:
//   As[rr*64 + c*8] holds global col (c ^ (rr&7))*8.
// bid >= 640: q projection + fused RoPE (A = xnorm bf16 via glds).
__global__ __launch_bounds__(256) void kvq_kernel(const float* __restrict__ tk,
                                                  const float* __restrict__ tv,
                                                  const ushort* __restrict__ Btk,
                                                  const ushort* __restrict__ Btv,
                                                  const ushort* __restrict__ xnorm,
                                                  const ushort* __restrict__ wqt,
                                                  ushort* __restrict__ Ck,
                                                  ushort* __restrict__ Vt,
                                                  ushort* __restrict__ Q) {
  __shared__ ushort As[128 * 64];
  __shared__ ushort Bs[64 * 64];
  int bid = blockIdx.x;
  int tid = threadIdx.x;
  int w = tid >> 6, lane = tid & 63;
  int lm = lane & 15, lq = lane >> 4;
  int arow = lane >> 3, acol = ((lane & 7) ^ arow) << 3;
  int kg[2] = {((lq) ^ (lm & 7)) << 3, ((4 + lq) ^ (lm & 7)) << 3};

  if (bid < 640) {
    int bz = bid / 320;
    int rem = bid - bz * 320;
    int bx = rem % 5, by = rem / 5;
    const float* Af = bz ? tv : tk;
    const ushort* Bt = bz ? Btv : Btk;
    int m0 = by * 128, n0 = bx * 64;
    int wm = (w & 1) * 64, wn = (w >> 1) * 32;
    floatx4 acc[4][2];
#pragma unroll
    for (int i = 0; i < 4; ++i)
#pragma unroll
      for (int j = 0; j < 2; ++j) acc[i][j] = (floatx4){0.f, 0.f, 0.f, 0.f};
    for (int k0 = 0; k0 < KV_DIM; k0 += 64) {
      // A: fp32 -> bf16 reg-staged, swizzled ds_write
#pragma unroll
      for (int s = 0; s < 4; ++s) {
        int rr = ((w << 2) + s) * 8 + arow;
        const float* src = Af + (size_t)(m0 + rr) * KV_DIM + k0 + ((lane & 7) << 3);
        float4 a0 = *(const float4*)src;
        float4 a1 = *(const float4*)(src + 4);
        uint4v pv = (uint4v){pk2bf(a0.x, a0.y), pk2bf(a0.z, a0.w),
                             pk2bf(a1.x, a1.y), pk2bf(a1.z, a1.w)};
        *(uint4v*)&As[rr * 64 + (((lane & 7) ^ arow) << 3)] = pv;
      }
      // B: bf16 weights via glds (pre-swizzled source)
#pragma unroll
      for (int s = 0; s < 2; ++s) {
        int g = (w << 1) + s;
        glds16(Bt + (size_t)(n0 + g * 8 + arow) * KV_DIM + k0 + acol, &Bs[g * 512]);
      }
      __syncthreads();
#pragma unroll
      for (int kc = 0; kc < 2; ++kc) {
        bf16x8 af[4], bf[2];
#pragma unroll
        for (int mt = 0; mt < 4; ++mt)
          af[mt] = *(const bf16x8*)&As[(wm + mt * 16 + lm) * 64 + kg[kc]];
#pragma unroll
        for (int nt = 0; nt < 2; ++nt)
          bf[nt] = *(const bf16x8*)&Bs[(wn + nt * 16 + lm) * 64 + kg[kc]];
#pragma unroll
        for (int mt = 0; mt < 4; ++mt)
#pragma unroll
          for (int nt = 0; nt < 2; ++nt)
            acc[mt][nt] = __builtin_amdgcn_mfma_f32_16x16x32_bf16(af[mt], bf[nt], acc[mt][nt], 0, 0, 0);
      }
      __syncthreads();
    }
    if (bz == 0) {  // K: row-major [token][KV_DIM]
#pragma unroll
      for (int mt = 0; mt < 4; ++mt)
#pragma unroll
        for (int nt = 0; nt < 2; ++nt)
#pragma unroll
          for (int r = 0; r < 4; ++r) {
            int row = m0 + wm + mt * 16 + lq * 4 + r;
            int col = n0 + wn + nt * 16 + lm;
            Ck[(size_t)row * KV_DIM + col] = f2bf(acc[mt][nt][r]);
          }
    } else {  // V: write transposed vt[(b*5+kvh)*64+d][token], 4 tokens packed
      int kvh = bx;
#pragma unroll
      for (int mt = 0; mt < 4; ++mt)
#pragma unroll
        for (int nt = 0; nt < 2; ++nt) {
          int d = wn + nt * 16 + lm;
          int grow = m0 + wm + mt * 16 + lq * 4;  // token base, 4-aligned
          int b = grow >> 11;
          int tok = grow & (LC - 1);
          size_t a = ((size_t)(b * KV_H + kvh) * 64 + d) * LC + tok;
          uint2v pk = (uint2v){pk2bf(acc[mt][nt][0], acc[mt][nt][1]),
                               pk2bf(acc[mt][nt][2], acc[mt][nt][3])};
          *(uint2v*)&Vt[a] = pk;
        }
    }
    return;
  }

  // ---- q projection + fused RoPE ----
  int r0 = bid - 640;
  int bx = r0 % 15, by = r0 / 15;
  int m0 = by * 128, n0 = bx * 64;
  int wm = (w & 1) * 64, wn = (w >> 1) * 16;  // cols wn+lm and +32
  floatx4 acc[4][2];
#pragma unroll
  for (int i = 0; i < 4; ++i)
#pragma unroll
    for (int j = 0; j < 2; ++j) acc[i][j] = (floatx4){0.f, 0.f, 0.f, 0.f};
  for (int k0 = 0; k0 < EMBD; k0 += 64) {
#pragma unroll
    for (int s = 0; s < 4; ++s) {
      int g = (w << 2) + s;
      glds16(xnorm + (size_t)(m0 + g * 8 + arow) * EMBD + k0 + acol, &As[g * 512]);
    }
#pragma unroll
    for (int s = 0; s < 2; ++s) {
      int g = (w << 1) + s;
      glds16(wqt + (size_t)(n0 + g * 8 + arow) * EMBD + k0 + acol, &Bs[g * 512]);
    }
    __syncthreads();
#pragma unroll
    for (int kc = 0; kc < 2; ++kc) {
      bf16x8 af[4], bf[2];
#pragma unroll
      for (int mt = 0; mt < 4; ++mt)
        af[mt] = *(const bf16x8*)&As[(wm + mt * 16 + lm) * 64 + kg[kc]];
#pragma unroll
      for (int nt = 0; nt < 2; ++nt) {
        int br = wn + nt * 32 + lm;
        bf[nt] = *(const bf16x8*)&Bs[br * 64 + (((kc * 4 + lq) ^ (br & 7)) << 3)];
      }
#pragma unroll
      for (int mt = 0; mt < 4; ++mt)
#pragma unroll
        for (int nt = 0; nt < 2; ++nt)
          acc[mt][nt] = __builtin_amdgcn_mfma_f32_16x16x32_bf16(af[mt], bf[nt], acc[mt][nt], 0, 0, 0);
    }
    __syncthreads();
  }
  int d = wn + lm;  // 0..31
  float invts = exp2f(-(float)d * 0.4152410118609203f);  // 10000^(-d/32)
#pragma unroll
  for (int mt = 0; mt < 4; ++mt)
#pragma unroll
    for (int r = 0; r < 4; ++r) {
      int row = m0 + wm + mt * 16 + lq * 4 + r;
      int l = row & (LL - 1);
      float th = (float)l * invts;
      float s, c;
      __sincosf(th, &s, &c);
      float q1 = acc[mt][0][r], q2 = acc[mt][1][r];
      size_t base = (size_t)row * QDIM + n0 + d;
      Q[base] = f2bf((q1 * c - q2 * s) * RSCALE);
      Q[base + 32] = f2bf((q2 * c + q1 * s) * RSCALE);
    }
}

// ---- fused gate+up: 128x64 tile, silu(g)*u epilogue (bf16 A via glds, 32KB LDS) ----
__global__ __launch_bounds__(256) void gemm_gateup(const ushort* __restrict__ A,
                                                   const ushort* __restrict__ Bg,
                                                   const ushort* __restrict__ Bu,
                                                   ushort* __restrict__ H,
                                                   int M, int N, int K) {
  __shared__ ushort As[128 * 64];
  __shared__ ushort Bs0[64 * 64];
  __shared__ ushort Bs1[64 * 64];
  int tid = threadIdx.x;
  int w = tid >> 6, lane = tid & 63;
  int lm = lane & 15, lq = lane >> 4;
  int m0 = blockIdx.y * 128, n0 = blockIdx.x * 64;
  int wm = (w & 1) * 64, wn = (w >> 1) * 32;
  int arow = lane >> 3, acol = ((lane & 7) ^ arow) << 3;
  int kg[2] = {((lq) ^ (lm & 7)) << 3, ((4 + lq) ^ (lm & 7)) << 3};
  floatx4 accg[4][2], accu[4][2];
#pragma unroll
  for (int i = 0; i < 4; ++i)
#pragma unroll
    for (int j = 0; j < 2; ++j) {
      accg[i][j] = (floatx4){0.f, 0.f, 0.f, 0.f};
      accu[i][j] = (floatx4){0.f, 0.f, 0.f, 0.f};
    }
  for (int k0 = 0; k0 < K; k0 += 64) {
#pragma unroll
    for (int s = 0; s < 4; ++s) {
      int g = (w << 2) + s;
      glds16(A + (size_t)(m0 + g * 8 + arow) * K + k0 + acol, &As[g * 512]);
    }
#pragma unroll
    for (int s = 0; s < 2; ++s) {
      int g = (w << 1) + s;
      glds16(Bg + (size_t)(n0 + g * 8 + arow) * K + k0 + acol, &Bs0[g * 512]);
      glds16(Bu + (size_t)(n0 + g * 8 + arow) * K + k0 + acol, &Bs1[g * 512]);
    }
    __syncthreads();
#pragma unroll
    for (int kc = 0; kc < 2; ++kc) {
      bf16x8 af[4], bg[2], bu[2];
#pragma unroll
      for (int mt = 0; mt < 4; ++mt)
        af[mt] = *(const bf16x8*)&As[(wm + mt * 16 + lm) * 64 + kg[kc]];
#pragma unroll
      for (int nt = 0; nt < 2; ++nt) {
        bg[nt] = *(const bf16x8*)&Bs0[(wn + nt * 16 + lm) * 64 + kg[kc]];
        bu[nt] = *(const bf16x8*)&Bs1[(wn + nt * 16 + lm) * 64 + kg[kc]];
      }
#pragma unroll
      for (int mt = 0; mt < 4; ++mt)
#pragma unroll
        for (int nt = 0; nt < 2; ++nt) {
          accg[mt][nt] = __builtin_amdgcn_mfma_f32_16x16x32_bf16(af[mt], bg[nt], accg[mt][nt], 0, 0, 0);
          accu[mt][nt] = __builtin_amdgcn_mfma_f32_16x16x32_bf16(af[mt], bu[nt], accu[mt][nt], 0, 0, 0);
        }
    }
    __syncthreads();
  }
#pragma unroll
  for (int mt = 0; mt < 4; ++mt)
#pragma unroll
    for (int nt = 0; nt < 2; ++nt)
#pragma unroll
      for (int r = 0; r < 4; ++r) {
        int row = m0 + wm + mt * 16 + lq * 4 + r;
        int col = n0 + wn + nt * 16 + lm;
        float gv = accg[mt][nt][r];
        float hv = gv / (1.f + __expf(-gv)) * accu[mt][nt][r];
        H[(size_t)row * N + col] = f2bf(hv);
      }
}

// ============ MFMA flash attention: 128-q blocks, NSP=8 ============
__global__ __launch_bounds__(256) void attn_kernel(const ushort* __restrict__ qb,
                                                   const ushort* __restrict__ kb,
                                                   const ushort* __restrict__ vt,
                                                   ushort* __restrict__ Op,
                                                   float* __restrict__ Ml) {
  int bid = blockIdx.x;
  int sp = bid & 7;
  int qt = (bid >> 3) & 3;
  int g = bid >> 5;  // 0..59
  int b = g / 15, h = g - b * 15;
  int kvh = h / 3;
  int l0 = qt * 128;
  int kv0 = sp * 256;
  __shared__ ushort Ks[64 * 64];
  __shared__ ushort Vs[64 * 64];
  __shared__ ushort Ps[4][32][72];           // 18432 B; per-wave P[32 q][64 keys]
  ushort* Qs = &Ps[0][0][0];                 // alias: 16 KB Q staging (dead after preload)
  int tid = threadIdx.x;
  int w = tid >> 6, lane = tid & 63, lm = lane & 15, lq = lane >> 4;
  int arow = lane >> 3, acol = ((lane & 7) ^ arow) << 3;
  int kg[2] = {((lq) ^ (lm & 7)) << 3, ((4 + lq) ^ (lm & 7)) << 3};
  const ushort* kbase = kb + (size_t)b * LC * KV_DIM + kvh * HEAD_DIM;
  const ushort* vbase = vt + (size_t)(b * KV_H + kvh) * 64 * LC;
#pragma unroll
  for (int s = 0; s < 4; ++s) {
    int gg = (w << 2) + s;
    glds16(qb + (size_t)(b * LL + l0 + gg * 8 + arow) * QDIM + h * HEAD_DIM + acol, &Qs[gg * 512]);
  }
  __syncthreads();
  bf16x8 aq[2][2];
#pragma unroll
  for (int q2 = 0; q2 < 2; ++q2) {
    int qr = w * 32 + q2 * 16 + lm;
    aq[q2][0] = *(const bf16x8*)&Qs[qr * 64 + kg[0]];
    aq[q2][1] = *(const bf16x8*)&Qs[qr * 64 + kg[1]];
  }
  bf16x8 bones;
  {
    short8 o = {0x3F80, 0x3F80, 0x3F80, 0x3F80, 0x3F80, 0x3F80, 0x3F80, 0x3F80};
    bones = *(bf16x8*)&o;
  }
  floatx4 oacc[4][2];  // [d-tile][q2]
#pragma unroll
  for (int i = 0; i < 4; ++i)
#pragma unroll
    for (int j = 0; j < 2; ++j) oacc[i][j] = (floatx4){0.f, 0.f, 0.f, 0.f};
  floatx4 lacc[2] = {(floatx4){0.f, 0.f, 0.f, 0.f}, (floatx4){0.f, 0.f, 0.f, 0.f}};

  for (int t = 0; t < 4; ++t) {
    int m0 = kv0 + t * 64;
#pragma unroll
    for (int s = 0; s < 2; ++s) {
      int gg = (w << 1) + s;
      glds16(kbase + (size_t)(m0 + gg * 8 + arow) * KV_DIM + acol, &Ks[gg * 512]);
      glds16(vbase + (size_t)(gg * 8 + arow) * LC + m0 + acol, &Vs[gg * 512]);
    }
    __syncthreads();  // also fences Qs->Ps alias on first iteration (aq reads drained)

    floatx4 sacc[4][2];
#pragma unroll
    for (int nt = 0; nt < 4; ++nt)
#pragma unroll
      for (int q2 = 0; q2 < 2; ++q2) sacc[nt][q2] = (floatx4){0.f, 0.f, 0.f, 0.f};
#pragma unroll
    for (int kc = 0; kc < 2; ++kc) {
#pragma unroll
      for (int nt = 0; nt < 4; ++nt) {
        bf16x8 bk = *(const bf16x8*)&Ks[(nt * 16 + lm) * 64 + kg[kc]];  // reused x2
#pragma unroll
        for (int q2 = 0; q2 < 2; ++q2)
          sacc[nt][q2] = __builtin_amdgcn_mfma_f32_16x16x32_bf16(bk, aq[q2][kc], sacc[nt][q2], 0, 0, 0);
      }
    }
#pragma unroll
    for (int nt = 0; nt < 4; ++nt)
#pragma unroll
      for (int q2 = 0; q2 < 2; ++q2) {
        float p0 = exp2f(sacc[nt][q2][0]);
        float p1 = exp2f(sacc[nt][q2][1]);
        float p2 = exp2f(sacc[nt][q2][2]);
        float p3 = exp2f(sacc[nt][q2][3]);
        uint2v pk = (uint2v){pk2bf(p0, p1), pk2bf(p2, p3)};
        *(uint2v*)&Ps[w][q2 * 16 + lm][nt * 16 + lq * 4] = pk;
      }
#pragma unroll
    for (int kc2 = 0; kc2 < 2; ++kc2) {
      bf16x8 ap[2];
      ap[0] = *(const bf16x8*)&Ps[w][lm][kc2 * 32 + lq * 8];
      ap[1] = *(const bf16x8*)&Ps[w][16 + lm][kc2 * 32 + lq * 8];
#pragma unroll
      for (int dt = 0; dt < 4; ++dt) {
        bf16x8 bv = *(const bf16x8*)&Vs[(dt * 16 + lm) * 64 + kg[kc2]];
#pragma unroll
        for (int q2 = 0; q2 < 2; ++q2)
          oacc[dt][q2] = __builtin_amdgcn_mfma_f32_16x16x32_bf16(ap[q2], bv, oacc[dt][q2], 0, 0, 0);
      }
      lacc[0] = __builtin_amdgcn_mfma_f32_16x16x32_bf16(ap[0], bones, lacc[0], 0, 0, 0);
      lacc[1] = __builtin_amdgcn_mfma_f32_16x16x32_bf16(ap[1], bones, lacc[1], 0, 0, 0);
    }
    __syncthreads();
  }
#pragma unroll
  for (int q2 = 0; q2 < 2; ++q2)
#pragma unroll
    for (int r = 0; r < 4; ++r) {
      int row = l0 + w * 32 + q2 * 16 + lq * 4 + r;
      size_t base = ((size_t)sp * (BB * LL) + b * LL + row) * QDIM + h * HEAD_DIM;
#pragma unroll
      for (int dt = 0; dt < 4; ++dt) Op[base + dt * 16 + lm] = f2bf(oacc[dt][q2][r]);
      if (lm == 0) Ml[((size_t)sp * (BB * LL) + b * LL + row) * Q_H + h] = lacc[q2][r];
    }
}

// combine NSP split partials -> ctx (vectorized short8; 2 rows per block)
__global__ __launch_bounds__(256) void combine_kernel(ushort* __restrict__ Op,
                                                      const float* __restrict__ Ml,
                                                      ushort* __restrict__ ctx) {
  int t = threadIdx.x;
  int half = t >> 7;
  int t2 = t & 127;
  if (t2 >= 120) return;
  int bl = blockIdx.x * 2 + half;
  int h = t2 >> 3;
  float lsum = 0.f;
#pragma unroll
  for (int s = 0; s < NSP; ++s) lsum += Ml[((size_t)s * (BB * LL) + bl) * Q_H + h];
  float inv = 1.f / lsum;
  size_t i0 = (size_t)bl * QDIM + t2 * 8;
  float o[8] = {0.f, 0.f, 0.f, 0.f, 0.f, 0.f, 0.f, 0.f};
#pragma unroll
  for (int s = 0; s < NSP; ++s) {
    short8 v = *(const short8*)(Op + (size_t)s * (BB * LL) * QDIM + i0);
#pragma unroll
    for (int j = 0; j < 8; ++j) o[j] += bf2f((ushort)v[j]);
  }
  short8 r;
#pragma unroll
  for (int j = 0; j < 8; ++j) r[j] = (short)f2bf(o[j] * inv);
  *(short8*)(ctx + i0) = r;
}

extern "C" void kernel_launch(void* const* d_in, const int* in_sizes, int n_in,
                              void* d_out, int out_size, void* d_ws, size_t ws_size,
                              hipStream_t stream) {
  const float* x      = (const float*)d_in[0];
  const float* text_k = (const float*)d_in[1];
  const float* text_v = (const float*)d_in[2];
  const float* ln1_w  = (const float*)d_in[3];
  const float* ln2_w  = (const float*)d_in[4];
  const float* wq     = (const float*)d_in[5];
  const float* wk     = (const float*)d_in[6];
  const float* wv     = (const float*)d_in[7];
  const float* wo     = (const float*)d_in[8];
  const float* w_gate = (const float*)d_in[9];
  const float* w_up   = (const float*)d_in[10];
  const float* w_down = (const float*)d_in[11];
  float* out = (float*)d_out;
  char* base = (char*)d_ws;

  const int BL = BB * LL;   // 2048

  ushort* xnorm = (ushort*)(base + 0);          // 3,145,728
  ushort* wqt   = (ushort*)(base + 3145728);    // 1,474,560
  ushort* wkt   = (ushort*)(base + 4620288);    //   204,800
  ushort* wvt   = (ushort*)(base + 4825088);    //   204,800
  ushort* wot   = (ushort*)(base + 5029888);    // 1,474,560
  ushort* wgt   = (ushort*)(base + 6504448);    // 3,145,728
  ushort* wut   = (ushort*)(base + 9650176);    // 3,145,728
  ushort* wdt   = (ushort*)(base + 12795904);   // 3,145,728
  ushort* kbuf  = (ushort*)(base + 15941632);   // 5,242,880
  ushort* vtb   = (ushort*)(base + 21184512);   // 5,242,880
  float*  x2    = (float*) (base + 26427392);   // 6,291,456
  ushort* qb    = (ushort*)(base + 32718848);   // 3,932,160
  float*  Ml    = (float*) (base + 47136768);   //   983,040 (NSP=8 x 122,880)
  char* SCR = base + 48119808;
  ushort* Op    = (ushort*)SCR;                 // NSP x 3,932,160 = 31,457,280
  ushort* ctxb  = (ushort*)SCR;                 // combine out, in-place over Op0
  ushort* gbuf  = (ushort*)(base + 15941632);   // alias kbuf+vtb (dead after attn)

  // mega prep: 7 weight transposes + rmsnorm1, one dispatch
  MD10 ds;
  ds.d[0] = {wq,     wqt,   nullptr, EMBD,    QDIM,    QDIM / 64,    0,    0};
  ds.d[1] = {wk,     wkt,   nullptr, KV_DIM,  KV_DIM,  KV_DIM / 64,  180,  0};
  ds.d[2] = {wv,     wvt,   nullptr, KV_DIM,  KV_DIM,  KV_DIM / 64,  205,  0};
  ds.d[3] = {wo,     wot,   nullptr, QDIM,    EMBD,    EMBD / 64,    230,  0};
  ds.d[4] = {w_gate, wgt,   nullptr, EMBD,    FFN_HID, FFN_HID / 64, 410,  0};
  ds.d[5] = {w_up,   wut,   nullptr, EMBD,    FFN_HID, FFN_HID / 64, 794,  0};
  ds.d[6] = {w_down, wdt,   nullptr, FFN_HID, EMBD,    EMBD / 64,    1178, 0};
  ds.d[7] = {x,      xnorm, ln1_w,   0, 0, 0, 1562, 2};
  ds.d[8] = {x,      xnorm, ln1_w,   0, 0, 0, 0x7fffffff, 2};  // dead
  ds.d[9] = {x,      xnorm, ln1_w,   0, 0, 0, 0x7fffffff, 2};  // dead
  const int nmega = 1562 + BL;  // 3610
  mega_prep<<<nmega, 256, 0, stream>>>(ds);

  // merged k/v projections (fp32 A, in-flight convert) + q projection/RoPE
  kvq_kernel<<<880, 256, 0, stream>>>(text_k, text_v, wkt, wvt, xnorm, wqt, kbuf, vtb, qb);

  // attention: 1920 blocks = 60 (b,h) x 4 q-tiles x 8 kv-splits; then combine
  attn_kernel<<<1920, 256, 0, stream>>>(qb, kbuf, vtb, Op, Ml);
  combine_kernel<<<BL / 2, 256, 0, stream>>>(Op, Ml, ctxb);

  // x2 = ctx @ wo + x  (128-tile chunk-paired GEMM, fused residual)
  gemm128r<<<dim3(EMBD / 64, BL / 128), 256, 0, stream>>>(ctxb, wot, x, x2, BL, EMBD, QDIM);

  rmsnorm_kernel<<<BL, 256, 0, stream>>>(x2, ln2_w, xnorm);
  gemm_gateup<<<dim3(FFN_HID / 64, BL / 128), 256, 0, stream>>>(xnorm, wgt, wut, gbuf, BL, FFN_HID, EMBD);
  // out = h @ w_down + x2  (128-tile chunk-paired GEMM, fused residual)
  gemm128r<<<dim3(EMBD / 64, BL / 128), 256, 0, stream>>>(gbuf, wdt, x2, out, BL, EMBD, FFN_HID);
}